// Round 15
// baseline (326.911 us; speedup 1.0000x reference)
//
#include <hip/hip_runtime.h>
#include <math.h>

#define DIMK 4096
#define NEXP 256
#define BM   64
#define BK32 32
#define NT   (DIMK / BK32)   // 128 k-tiles
#define NGRP 8
#define GSZ  32
#define TOPKG 4
#define TOPKE 8
#define BTILE 49152          // ws bytes per k-tile (3 planes * 16 KB)
#define WS_NEED ((size_t)NT * BTILE)   // 6,291,456 B of bf16 w-planes

// LDS map (aliased by sc[64][257] f64 = 131584 B):
//   X dbuf [2][3 planes][4 chunks][64 tok][16 B] at 0 (24576 B); B never in LDS.
#define XPLANE  4096
#define XTILE   12288
#define SMEM_SZ 131584

typedef __bf16 bf16x8 __attribute__((ext_vector_type(8)));
typedef float f32x4 __attribute__((ext_vector_type(4)));

// ---- f32 -> 3x bf16 split (residuals Sterbenz-exact) ----
__device__ __forceinline__ void decomp8(const float v[8], uint4& H, uint4& M, uint4& L) {
  union U { __bf16 b[8]; uint4 u; } h, m, l;
#pragma unroll
  for (int i = 0; i < 8; ++i) {
    float xv = v[i];
    __bf16 hb = (__bf16)xv;
    float r1 = xv - (float)hb;
    __bf16 mb = (__bf16)r1;
    float r2 = r1 - (float)mb;
    h.b[i] = hb; m.b[i] = mb; l.b[i] = (__bf16)r2;
  }
  H = h.u; M = m.u; L = l.u;
}

// ================= pre-kernel: decompose w into frag-native ws layout ========
// ws block for (tile t, plane p, expert-block eb) = 1024 B at ((t*3+p)*16+eb)*1024.
// Within a block: lane = ((k&31)>>3)*16 + (e&15) holds 8 bf16 = w[e][t*32+(lane>>4)*8+j].
__global__ __launch_bounds__(256) void w_split_kernel(const float* __restrict__ wgt,
                                                      unsigned char* __restrict__ ws) {
  const int g = blockIdx.x * 256 + threadIdx.x;   // 131072 threads
  const int e = g >> 9;                            // expert 0..255
  const int k0 = (g & 511) << 3;                   // k chunk of 8
  const int kt = k0 >> 5;
  const int chunk = (k0 & 31) >> 3;
  const int lane = chunk * 16 + (e & 15);
  const int eb = e >> 4;
  float v[8];
  float4 a = *(const float4*)(wgt + (long)e * DIMK + k0);
  float4 b = *(const float4*)(wgt + (long)e * DIMK + k0 + 4);
  v[0]=a.x; v[1]=a.y; v[2]=a.z; v[3]=a.w; v[4]=b.x; v[5]=b.y; v[6]=b.z; v[7]=b.w;
  uint4 H, M, L;
  decomp8(v, H, M, L);
  const long base = ((long)(kt * 3) * 16 + eb) * 1024 + lane * 16;
  *(uint4*)(ws + base)             = H;   // p=0
  *(uint4*)(ws + base + 16 * 1024) = M;   // p=1
  *(uint4*)(ws + base + 32 * 1024) = L;   // p=2
}

// ============== main kernel: 64 tokens x 256 experts, 16 waves (1024 thr) ====
// Per wave: 16 tokens x 64 experts (1x4 16x16 tiles), 24 MFMA/tile.
// 16 waves/block = 4 waves/SIMD at 1 block/CU -> VGPR budget 128 (small state
// fits: acc 32 + D 16 + 2x B-set 32 + A 12). A via small LDS dbuf; B direct
// global->reg, alternating named sets so loads lead use by ~8 MFMAs.
__global__ __launch_bounds__(1024) void moe_gate_mfma(
    const float* __restrict__ x, const unsigned char* __restrict__ ws,
    const float* __restrict__ bias, float* __restrict__ outw, float* __restrict__ outi) {
  __shared__ __align__(16) unsigned char smem[SMEM_SZ];
  double* sc = (double*)smem;

  const int tid = threadIdx.x;      // 0..1023
  const int lane = tid & 63;
  const int l15 = lane & 15;
  const int wid = tid >> 6;         // 0..15
  const int wr = wid >> 2;          // token quarter 0..3 (16 tokens)
  const int wc = wid & 3;           // expert quarter 0..3 (64 experts)
  const long bm0 = (long)blockIdx.x * BM;

  // x staging role (tid<256): token = tid>>2 (0..63), chunk = tid&3 (8 k each)
  const int xtok = tid >> 2;
  const int xch = tid & 3;
  const bool stager = (tid < 256);
  const float* xptr = x + (bm0 + xtok) * (long)DIMK + xch * 8;
  const int xwoff = xch * 1024 + xtok * 16;   // within a plane

  // B frag base: lane's 16 B of (tile t, plane p, expert block wc*4+ct)
  //   = wsb + t*BTILE + p*16384 + ct*1024
  const unsigned char* wsb = ws + (wc * 4) * 1024 + lane * 16;

  f32x4 D[4];
  double acc[4][4];
#pragma unroll
  for (int ct = 0; ct < 4; ++ct) {
    D[ct] = (f32x4){0.f, 0.f, 0.f, 0.f};
#pragma unroll
    for (int r = 0; r < 4; ++r) acc[ct][r] = 0.0;
  }

  float4 xa, xb4;

  // ---- prologue: x(0) -> LDS buf0 ----
  if (stager) {
    xa = *(const float4*)(xptr);
    xb4 = *(const float4*)(xptr + 4);
    float v[8] = {xa.x, xa.y, xa.z, xa.w, xb4.x, xb4.y, xb4.z, xb4.w};
    uint4 H, M, L;
    decomp8(v, H, M, L);
    *(uint4*)(smem + 0 * XPLANE + xwoff) = H;
    *(uint4*)(smem + 1 * XPLANE + xwoff) = M;
    *(uint4*)(smem + 2 * XPLANE + xwoff) = L;
  }
  __syncthreads();

#define MM(A, B, CT) \
  D[CT] = __builtin_amdgcn_mfma_f32_16x16x32_bf16(A, B, D[CT], 0, 0, 0)
#define P4(A, B0, B1, B2, B3) \
  MM(A, B0, 0); MM(A, B1, 1); MM(A, B2, 2); MM(A, B3, 3)

#pragma unroll 1
  for (int t = 0; t < NT; ++t) {
    const int buf = t & 1, nbuf = buf ^ 1;
    const bool more = (t + 1 < NT);
    // 1) x(t+1) global loads issued first (stagers only)
    if (more && stager) {
      xa = *(const float4*)(xptr + (t + 1) * BK32);
      xb4 = *(const float4*)(xptr + (t + 1) * BK32 + 4);
    }
    // 2) A-frags(t) from LDS (3 planes, 1 row-tile each)
    const unsigned char* xbuf = smem + buf * XTILE;
    const int ao = (lane >> 4) * 1024 + (wr * 16 + l15) * 16;
    bf16x8 ah = *(const bf16x8*)(xbuf + 0 * XPLANE + ao);
    bf16x8 am = *(const bf16x8*)(xbuf + 1 * XPLANE + ao);
    bf16x8 al = *(const bf16x8*)(xbuf + 2 * XPLANE + ao);
    // 3) MFMA cluster; B per-plane direct global->reg, alternating sets
    const unsigned char* bt = wsb + (long)t * BTILE;
    bf16x8 pA0, pA1, pA2, pA3, pB0, pB1, pB2, pB3;
    __builtin_amdgcn_s_setprio(1);
    pA0 = *(const bf16x8*)(bt + 0 * 16384 + 0 * 1024);   // plane hi
    pA1 = *(const bf16x8*)(bt + 0 * 16384 + 1 * 1024);
    pA2 = *(const bf16x8*)(bt + 0 * 16384 + 2 * 1024);
    pA3 = *(const bf16x8*)(bt + 0 * 16384 + 3 * 1024);
    P4(ah, pA0, pA1, pA2, pA3);   // hi * w_hi
    P4(am, pA0, pA1, pA2, pA3);   // mid * w_hi
    pB0 = *(const bf16x8*)(bt + 1 * 16384 + 0 * 1024);   // plane mid (early)
    pB1 = *(const bf16x8*)(bt + 1 * 16384 + 1 * 1024);
    pB2 = *(const bf16x8*)(bt + 1 * 16384 + 2 * 1024);
    pB3 = *(const bf16x8*)(bt + 1 * 16384 + 3 * 1024);
    P4(al, pA0, pA1, pA2, pA3);   // lo * w_hi (last bA use)
    pA0 = *(const bf16x8*)(bt + 2 * 16384 + 0 * 1024);   // plane lo (early)
    pA1 = *(const bf16x8*)(bt + 2 * 16384 + 1 * 1024);
    pA2 = *(const bf16x8*)(bt + 2 * 16384 + 2 * 1024);
    pA3 = *(const bf16x8*)(bt + 2 * 16384 + 3 * 1024);
    P4(ah, pB0, pB1, pB2, pB3);   // hi * w_mid
    P4(am, pB0, pB1, pB2, pB3);   // mid * w_mid
    P4(ah, pA0, pA1, pA2, pA3);   // hi * w_lo
    __builtin_amdgcn_s_setprio(0);
    // 4) late x write: decomp staged regs -> LDS(nbuf)
    if (more && stager) {
      float v[8] = {xa.x, xa.y, xa.z, xa.w, xb4.x, xb4.y, xb4.z, xb4.w};
      uint4 H, M, L;
      decomp8(v, H, M, L);
      unsigned char* xw = smem + nbuf * XTILE + xwoff;
      *(uint4*)(xw + 0 * XPLANE) = H;
      *(uint4*)(xw + 1 * XPLANE) = M;
      *(uint4*)(xw + 2 * XPLANE) = L;
    }
    // 5) flush f32 -> f64 every 2 tiles (64 k)
    if (t & 1) {
#pragma unroll
      for (int ct = 0; ct < 4; ++ct) {
#pragma unroll
        for (int r = 0; r < 4; ++r) acc[ct][r] += (double)D[ct][r];
        D[ct] = (f32x4){0.f, 0.f, 0.f, 0.f};
      }
    }
    // 6) one barrier per tile (guards only the small x dbuf)
    __syncthreads();
  }
#undef P4
#undef MM

  // ---- epilogue: f64 sigmoid + bias -> sc (aliases staging LDS) ----
#pragma unroll
  for (int ct = 0; ct < 4; ++ct) {
    const int col = wc * 64 + ct * 16 + l15;
    const double bd = (double)bias[col];
#pragma unroll
    for (int r = 0; r < 4; ++r) {
      const int row = wr * 16 + (lane >> 4) * 4 + r;
      const double s = 1.0 / (1.0 + exp(-acc[ct][r]));  // original score
      sc[row * 257 + col] = s + bd;                     // biased, for ranking
    }
  }
  __syncthreads();

  // ---- routing: one lane per token (verbatim from the passing kernels) ----
  if (tid < BM) {
    double* row = sc + tid * 257;
    double gs[NGRP];
#pragma unroll
    for (int g = 0; g < NGRP; ++g) {
      double m1 = -1e300, m2 = -1e300;
      for (int e = 0; e < GSZ; ++e) {
        double v = row[g * GSZ + e];
        if (v > m1) { m2 = m1; m1 = v; }
        else if (v > m2) { m2 = v; }
      }
      gs[g] = m1 + m2;
    }
    unsigned msk = 0;
#pragma unroll
    for (int g = 0; g < NGRP; ++g) {
      int cnt = 0;
#pragma unroll
      for (int h = 0; h < NGRP; ++h)
        cnt += ((gs[h] > gs[g]) || (gs[h] == gs[g] && h > g)) ? 1 : 0;
      if (cnt < TOPKG) msk |= (1u << g);
    }
    int g0 = __ffs(msk) - 1; msk &= msk - 1;
    int g1 = __ffs(msk) - 1; msk &= msk - 1;
    int g2 = __ffs(msk) - 1; msk &= msk - 1;
    int g3 = __ffs(msk) - 1;

    double wv[TOPKE];
    float iv[TOPKE];
#pragma unroll
    for (int r8 = 0; r8 < TOPKE; ++r8) {
      double best = -1e300;
      int bi = 0;
      {
        int gg = g0;
        for (int e = 0; e < GSZ; ++e) { double v = row[gg * GSZ + e]; if (v >= best) { best = v; bi = gg * GSZ + e; } }
        gg = g1;
        for (int e = 0; e < GSZ; ++e) { double v = row[gg * GSZ + e]; if (v >= best) { best = v; bi = gg * GSZ + e; } }
        gg = g2;
        for (int e = 0; e < GSZ; ++e) { double v = row[gg * GSZ + e]; if (v >= best) { best = v; bi = gg * GSZ + e; } }
        gg = g3;
        for (int e = 0; e < GSZ; ++e) { double v = row[gg * GSZ + e]; if (v >= best) { best = v; bi = gg * GSZ + e; } }
      }
      row[bi] = -1e300;
      wv[7 - r8] = best - (double)bias[bi];
      iv[7 - r8] = (float)bi;
    }
    double sum = 0.0;
#pragma unroll
    for (int p = 0; p < TOPKE; ++p) sum += wv[p];
    const double den = sum + 1e-20;
    const long trow = bm0 + tid;
#pragma unroll
    for (int p = 0; p < TOPKE; ++p) {
      outw[trow * 8 + p] = (float)(wv[p] / den * 2.5);
      outi[trow * 8 + p] = iv[p];
    }
  }
}

// ================= fallback: round-2 f64-VALU kernel (known-PASS) ============
#define BMF  64
#define BKF 16
#define LXSF 68
__global__ __launch_bounds__(256, 1) void moe_gate_f64(
    const float* __restrict__ x, const float* __restrict__ wgt,
    const float* __restrict__ bias, float* __restrict__ outw,
    float* __restrict__ outi) {
  __shared__ __align__(16) unsigned char smem[64 * 257 * 8];
  float* lw = (float*)smem;
  float* lx = (float*)(smem + 32768);
  double* sc = (double*)smem;
  const int tid = threadIdx.x;
  const long bm0 = (long)blockIdx.x * BMF;
  const int rg = tid >> 5;
  const int cg = tid & 31;
  const int sxr = tid >> 2;
  const int sxj = (tid & 3) << 2;
  const float* xrow = x + (bm0 + sxr) * (long)DIMK + sxj;
  const float* wrow = wgt + (long)tid * DIMK;
  double acc[8][8];
#pragma unroll
  for (int i = 0; i < 8; ++i)
#pragma unroll
    for (int j = 0; j < 8; ++j) acc[i][j] = 0.0;
#define LWF(b, k, e) lw[((b)*BKF + (k)) * NEXP + (e)]
#define LXF(b, k, r) lx[((b)*BKF + (k)) * LXSF + (r)]
  {
    float4 xv = *(const float4*)(xrow);
#pragma unroll
    for (int c = 0; c < 4; ++c) LXF(0, sxj + c, sxr) = ((const float*)&xv)[c];
#pragma unroll
    for (int jj = 0; jj < 4; ++jj) {
      float4 wv = *(const float4*)(wrow + jj * 4);
#pragma unroll
      for (int c = 0; c < 4; ++c) LWF(0, jj * 4 + c, tid) = ((const float*)&wv)[c];
    }
  }
  __syncthreads();
  const int NTF = DIMK / BKF;
  for (int kt = 0; kt < NTF; ++kt) {
    const int b = kt & 1;
    if (kt + 1 < NTF) {
      const int k0 = (kt + 1) * BKF;
      const int nb = b ^ 1;
      float4 xv = *(const float4*)(xrow + k0);
      float4 wv0 = *(const float4*)(wrow + k0);
      float4 wv1 = *(const float4*)(wrow + k0 + 4);
      float4 wv2 = *(const float4*)(wrow + k0 + 8);
      float4 wv3 = *(const float4*)(wrow + k0 + 12);
#pragma unroll
      for (int c = 0; c < 4; ++c) LXF(nb, sxj + c, sxr) = ((const float*)&xv)[c];
#pragma unroll
      for (int c = 0; c < 4; ++c) LWF(nb, 0 + c, tid) = ((const float*)&wv0)[c];
#pragma unroll
      for (int c = 0; c < 4; ++c) LWF(nb, 4 + c, tid) = ((const float*)&wv1)[c];
#pragma unroll
      for (int c = 0; c < 4; ++c) LWF(nb, 8 + c, tid) = ((const float*)&wv2)[c];
#pragma unroll
      for (int c = 0; c < 4; ++c) LWF(nb, 12 + c, tid) = ((const float*)&wv3)[c];
    }
#pragma unroll
    for (int k = 0; k < BKF; ++k) {
      float4 a0 = *(const float4*)(&LXF(b, k, rg * 8));
      float4 a1 = *(const float4*)(&LXF(b, k, rg * 8 + 4));
      double ad[8] = {(double)a0.x, (double)a0.y, (double)a0.z, (double)a0.w,
                      (double)a1.x, (double)a1.y, (double)a1.z, (double)a1.w};
      double bd[8];
#pragma unroll
      for (int j = 0; j < 4; ++j) {
        float2 bb = *(const float2*)(&LWF(b, k, cg * 2 + 64 * j));
        bd[2 * j] = (double)bb.x;
        bd[2 * j + 1] = (double)bb.y;
      }
#pragma unroll
      for (int i = 0; i < 8; ++i)
#pragma unroll
        for (int j = 0; j < 8; ++j) acc[i][j] += ad[i] * bd[j];
    }
    __syncthreads();
  }
  double bc[8];
#pragma unroll
  for (int j = 0; j < 4; ++j) {
    bc[2 * j] = (double)bias[cg * 2 + 64 * j];
    bc[2 * j + 1] = (double)bias[cg * 2 + 64 * j + 1];
  }
#pragma unroll
  for (int i = 0; i < 8; ++i) {
    const int r = rg * 8 + i;
#pragma unroll
    for (int jq = 0; jq < 8; ++jq) {
      const int col = cg * 2 + 64 * (jq >> 1) + (jq & 1);
      double s = 1.0 / (1.0 + exp(-acc[i][jq]));
      sc[r * 257 + col] = s + bc[jq];
    }
  }
  __syncthreads();
  if (tid < BMF) {
    double* row = sc + tid * 257;
    double gs[NGRP];
#pragma unroll
    for (int g = 0; g < NGRP; ++g) {
      double m1 = -1e300, m2 = -1e300;
      for (int e = 0; e < GSZ; ++e) {
        double v = row[g * GSZ + e];
        if (v > m1) { m2 = m1; m1 = v; }
        else if (v > m2) { m2 = v; }
      }
      gs[g] = m1 + m2;
    }
    unsigned msk = 0;
#pragma unroll
    for (int g = 0; g < NGRP; ++g) {
      int cnt = 0;
#pragma unroll
      for (int h = 0; h < NGRP; ++h)
        cnt += ((gs[h] > gs[g]) || (gs[h] == gs[g] && h > g)) ? 1 : 0;
      if (cnt < TOPKG) msk |= (1u << g);
    }
    int g0 = __ffs(msk) - 1; msk &= msk - 1;
    int g1 = __ffs(msk) - 1; msk &= msk - 1;
    int g2 = __ffs(msk) - 1; msk &= msk - 1;
    int g3 = __ffs(msk) - 1;
    double wv[TOPKE];
    float iv[TOPKE];
#pragma unroll
    for (int r8 = 0; r8 < TOPKE; ++r8) {
      double best = -1e300;
      int bi = 0;
      {
        int gg = g0;
        for (int e = 0; e < GSZ; ++e) { double v = row[gg * GSZ + e]; if (v >= best) { best = v; bi = gg * GSZ + e; } }
        gg = g1;
        for (int e = 0; e < GSZ; ++e) { double v = row[gg * GSZ + e]; if (v >= best) { best = v; bi = gg * GSZ + e; } }
        gg = g2;
        for (int e = 0; e < GSZ; ++e) { double v = row[gg * GSZ + e]; if (v >= best) { best = v; bi = gg * GSZ + e; } }
        gg = g3;
        for (int e = 0; e < GSZ; ++e) { double v = row[gg * GSZ + e]; if (v >= best) { best = v; bi = gg * GSZ + e; } }
      }
      row[bi] = -1e300;
      wv[7 - r8] = best - (double)bias[bi];
      iv[7 - r8] = (float)bi;
    }
    double sum = 0.0;
#pragma unroll
    for (int p = 0; p < TOPKE; ++p) sum += wv[p];
    const double den = sum + 1e-20;
    const long trow = bm0 + tid;
#pragma unroll
    for (int p = 0; p < TOPKE; ++p) {
      outw[trow * 8 + p] = (float)(wv[p] / den * 2.5);
      outi[trow * 8 + p] = iv[p];
    }
  }
}

extern "C" void kernel_launch(void* const* d_in, const int* in_sizes, int n_in,
                              void* d_out, int out_size, void* d_ws, size_t ws_size,
                              hipStream_t stream) {
  const float* x = (const float*)d_in[0];
  const float* w = (const float*)d_in[1];
  const float* b = (const float*)d_in[2];
  const int ntok = in_sizes[0] / DIMK;  // 16384
  float* outw = (float*)d_out;
  float* outi = outw + (size_t)ntok * 8;
  if (ws_size >= WS_NEED) {
    hipLaunchKernelGGL(w_split_kernel, dim3(512), dim3(256), 0, stream,
                       w, (unsigned char*)d_ws);
    hipLaunchKernelGGL(moe_gate_mfma, dim3(ntok / BM), dim3(1024), 0, stream,
                       x, (const unsigned char*)d_ws, b, outw, outi);
  } else {
    hipLaunchKernelGGL(moe_gate_f64, dim3(ntok / 64), dim3(256), 0, stream,
                       x, w, b, outw, outi);
  }
}

// Round 16
// 228.018 us; speedup vs baseline: 1.4337x; 1.4337x over previous
//
#include <hip/hip_runtime.h>
#include <math.h>

#define DIMK 4096
#define NEXP 256
#define BM   64
#define BK32 32
#define NT   (DIMK / BK32)   // 128 k-tiles
#define NGRP 8
#define GSZ  32
#define TOPKG 4
#define TOPKE 8
#define BTILE 49152          // ws bytes per k-tile (3 planes * 16 KB)
#define WS_NEED ((size_t)NT * BTILE)   // 6,291,456 B of bf16 w-planes

// LDS map (aliased by sc[64][257] f64 = 131584 B):
//   X dbuf [2][3 planes][4 chunks][64 tok][16 B] at 0 (24576 B); B never in LDS.
#define XTILE   12288
#define SMEM_SZ 131584

typedef __bf16 bf16x8 __attribute__((ext_vector_type(8)));
typedef float f32x4 __attribute__((ext_vector_type(4)));

// T4 counted-wait barrier: only LDS (x-dbuf) needs visibility; B prefetch
// loads are plain global->REGISTER loads, so they may legally stay in flight
// across the barrier (compiler emits counted vmcnt at first use next tile).
// __syncthreads() would drain vmcnt(0) and expose L2 latency every tile.
__device__ __forceinline__ void block_sync_lds_only() {
  asm volatile("s_waitcnt lgkmcnt(0)" ::: "memory");
  __builtin_amdgcn_s_barrier();
  asm volatile("" ::: "memory");
}

// ---- f32 -> 3x bf16 split (residuals Sterbenz-exact) ----
__device__ __forceinline__ void decomp8(const float v[8], uint4& H, uint4& M, uint4& L) {
  union U { __bf16 b[8]; uint4 u; } h, m, l;
#pragma unroll
  for (int i = 0; i < 8; ++i) {
    float xv = v[i];
    __bf16 hb = (__bf16)xv;
    float r1 = xv - (float)hb;
    __bf16 mb = (__bf16)r1;
    float r2 = r1 - (float)mb;
    h.b[i] = hb; m.b[i] = mb; l.b[i] = (__bf16)r2;
  }
  H = h.u; M = m.u; L = l.u;
}

__device__ __forceinline__ void decomp4(float4 v, uint2& H, uint2& M, uint2& L) {
  union U { __bf16 b[4]; uint2 u; } h, m, l;
  float vv[4] = {v.x, v.y, v.z, v.w};
#pragma unroll
  for (int i = 0; i < 4; ++i) {
    float xv = vv[i];
    __bf16 hb = (__bf16)xv;
    float r1 = xv - (float)hb;
    __bf16 mb = (__bf16)r1;
    float r2 = r1 - (float)mb;
    h.b[i] = hb; m.b[i] = mb; l.b[i] = (__bf16)r2;
  }
  H = h.u; M = m.u; L = l.u;
}

// ================= pre-kernel: decompose w into frag-native ws layout ========
// ws block for (tile t, plane p, expert-block eb) = 1024 B at ((t*3+p)*16+eb)*1024.
// Within a block: lane = ((k&31)>>3)*16 + (e&15) holds 8 bf16 = w[e][t*32+(lane>>4)*8+j].
__global__ __launch_bounds__(256) void w_split_kernel(const float* __restrict__ wgt,
                                                      unsigned char* __restrict__ ws) {
  const int g = blockIdx.x * 256 + threadIdx.x;   // 131072 threads
  const int e = g >> 9;                            // expert 0..255
  const int k0 = (g & 511) << 3;                   // k chunk of 8
  const int kt = k0 >> 5;
  const int chunk = (k0 & 31) >> 3;
  const int lane = chunk * 16 + (e & 15);
  const int eb = e >> 4;
  float v[8];
  float4 a = *(const float4*)(wgt + (long)e * DIMK + k0);
  float4 b = *(const float4*)(wgt + (long)e * DIMK + k0 + 4);
  v[0]=a.x; v[1]=a.y; v[2]=a.z; v[3]=a.w; v[4]=b.x; v[5]=b.y; v[6]=b.z; v[7]=b.w;
  uint4 H, M, L;
  decomp8(v, H, M, L);
  const long base = ((long)(kt * 3) * 16 + eb) * 1024 + lane * 16;
  *(uint4*)(ws + base)             = H;   // p=0
  *(uint4*)(ws + base + 16 * 1024) = M;   // p=1
  *(uint4*)(ws + base + 32 * 1024) = L;   // p=2
}

// ================= main kernel: 64 tokens x 256 experts, 8 waves =============
// A (x-planes) through a small LDS dbuf; B (w-planes) direct global->register
// with per-plane rolling prefetch. Barrier = lgkmcnt-only (T4): B loads span it.
__global__ __launch_bounds__(512) void moe_gate_mfma(
    const float* __restrict__ x, const unsigned char* __restrict__ ws,
    const float* __restrict__ bias, float* __restrict__ outw, float* __restrict__ outi) {
  __shared__ __align__(16) unsigned char smem[SMEM_SZ];
  double* sc = (double*)smem;

  const int tid = threadIdx.x;      // 0..511
  const int lane = tid & 63;
  const int l15 = lane & 15;
  const int wid = tid >> 6;         // 0..7
  const int wr = wid >> 2;          // token half 0..1
  const int wc = wid & 3;           // expert quarter 0..3
  const long bm0 = (long)blockIdx.x * BM;

  // x staging role: token = tid>>3 (0..63), q = tid&7 (4 f32 each) -> coalesced
  const int xtok = tid >> 3;
  const int xq = tid & 7;
  const float* xptr = x + (bm0 + xtok) * (long)DIMK + xq * 4;
  const int xwoff = (xq >> 1) * 1024 + xtok * 16 + (xq & 1) * 8;

  // B frag base: lane's 16 B within (plane p, expert block wc*4+ct) at tile t:
  //   wsb + t*BTILE + p*16384 + ct*1024
  const unsigned char* wsb = ws + (wc * 4) * 1024 + lane * 16;

  f32x4 D[2][4];
  double acc[2][4][4];
#pragma unroll
  for (int rt = 0; rt < 2; ++rt)
#pragma unroll
    for (int ct = 0; ct < 4; ++ct) {
      D[rt][ct] = (f32x4){0.f, 0.f, 0.f, 0.f};
#pragma unroll
      for (int r = 0; r < 4; ++r) acc[rt][ct][r] = 0.0;
    }

  float4 xv;
  bf16x8 bh0, bh1, bh2, bh3, bm0r, bm1r, bm2r, bm3r, bl0, bl1, bl2, bl3;

  // ---- prologue: B(0) -> regs; x(0) -> LDS buf0 ----
  bh0 = *(const bf16x8*)(wsb + 0 * 16384 + 0 * 1024);
  bh1 = *(const bf16x8*)(wsb + 0 * 16384 + 1 * 1024);
  bh2 = *(const bf16x8*)(wsb + 0 * 16384 + 2 * 1024);
  bh3 = *(const bf16x8*)(wsb + 0 * 16384 + 3 * 1024);
  bm0r = *(const bf16x8*)(wsb + 1 * 16384 + 0 * 1024);
  bm1r = *(const bf16x8*)(wsb + 1 * 16384 + 1 * 1024);
  bm2r = *(const bf16x8*)(wsb + 1 * 16384 + 2 * 1024);
  bm3r = *(const bf16x8*)(wsb + 1 * 16384 + 3 * 1024);
  bl0 = *(const bf16x8*)(wsb + 2 * 16384 + 0 * 1024);
  bl1 = *(const bf16x8*)(wsb + 2 * 16384 + 1 * 1024);
  bl2 = *(const bf16x8*)(wsb + 2 * 16384 + 2 * 1024);
  bl3 = *(const bf16x8*)(wsb + 2 * 16384 + 3 * 1024);
  xv = *(const float4*)(xptr);
  {
    uint2 H, M, L;
    decomp4(xv, H, M, L);
    *(uint2*)(smem + xwoff + 0 * 4096) = H;
    *(uint2*)(smem + xwoff + 1 * 4096) = M;
    *(uint2*)(smem + xwoff + 2 * 4096) = L;
  }
  __syncthreads();

#define MM(A, B, RT, CT) \
  D[RT][CT] = __builtin_amdgcn_mfma_f32_16x16x32_bf16(A, B, D[RT][CT], 0, 0, 0)
#define P8(A0, A1, B0, B1, B2, B3) \
  MM(A0, B0, 0, 0); MM(A0, B1, 0, 1); MM(A0, B2, 0, 2); MM(A0, B3, 0, 3); \
  MM(A1, B0, 1, 0); MM(A1, B1, 1, 1); MM(A1, B2, 1, 2); MM(A1, B3, 1, 3)

  long bo_n = BTILE;   // byte offset of tile t+1 in ws (clamped at the end)

#pragma unroll 1
  for (int t = 0; t < NT; ++t) {
    const int buf = t & 1, nbuf = buf ^ 1;
    const bool more = (t + 1 < NT);
    // 1) x(t+1) global load issued first
    if (more) xv = *(const float4*)(xptr + (t + 1) * BK32);
    // 2) A-frags(t) from LDS
    const unsigned char* xb = smem + buf * XTILE;
    const int ao0 = (lane >> 4) * 1024 + (wr * 32 + l15) * 16;
    const int ao1 = ao0 + 256;  // +16 tokens
    bf16x8 ah0 = *(const bf16x8*)(xb + 0 * 4096 + ao0);
    bf16x8 ah1 = *(const bf16x8*)(xb + 0 * 4096 + ao1);
    bf16x8 am0 = *(const bf16x8*)(xb + 1 * 4096 + ao0);
    bf16x8 am1 = *(const bf16x8*)(xb + 1 * 4096 + ao1);
    bf16x8 al0 = *(const bf16x8*)(xb + 2 * 4096 + ao0);
    bf16x8 al1 = *(const bf16x8*)(xb + 2 * 4096 + ao1);
    // 3) MFMA passes with rolling per-plane B prefetch (WAR enforces order)
    __builtin_amdgcn_s_setprio(1);
    P8(ah0, ah1, bh0, bh1, bh2, bh3);     // hi * w_hi
    P8(am0, am1, bh0, bh1, bh2, bh3);     // mid * w_hi
    P8(al0, al1, bh0, bh1, bh2, bh3);     // lo * w_hi
    bh0 = *(const bf16x8*)(wsb + bo_n + 0 * 16384 + 0 * 1024);
    bh1 = *(const bf16x8*)(wsb + bo_n + 0 * 16384 + 1 * 1024);
    bh2 = *(const bf16x8*)(wsb + bo_n + 0 * 16384 + 2 * 1024);
    bh3 = *(const bf16x8*)(wsb + bo_n + 0 * 16384 + 3 * 1024);
    P8(ah0, ah1, bm0r, bm1r, bm2r, bm3r); // hi * w_mid
    P8(am0, am1, bm0r, bm1r, bm2r, bm3r); // mid * w_mid
    bm0r = *(const bf16x8*)(wsb + bo_n + 1 * 16384 + 0 * 1024);
    bm1r = *(const bf16x8*)(wsb + bo_n + 1 * 16384 + 1 * 1024);
    bm2r = *(const bf16x8*)(wsb + bo_n + 1 * 16384 + 2 * 1024);
    bm3r = *(const bf16x8*)(wsb + bo_n + 1 * 16384 + 3 * 1024);
    P8(ah0, ah1, bl0, bl1, bl2, bl3);     // hi * w_lo
    bl0 = *(const bf16x8*)(wsb + bo_n + 2 * 16384 + 0 * 1024);
    bl1 = *(const bf16x8*)(wsb + bo_n + 2 * 16384 + 1 * 1024);
    bl2 = *(const bf16x8*)(wsb + bo_n + 2 * 16384 + 2 * 1024);
    bl3 = *(const bf16x8*)(wsb + bo_n + 2 * 16384 + 3 * 1024);
    __builtin_amdgcn_s_setprio(0);
    // 4) late x write (T14): decomp staged reg -> LDS(nbuf)
    if (more) {
      uint2 H, M, L;
      decomp4(xv, H, M, L);
      unsigned char* xw = smem + nbuf * XTILE + xwoff;
      *(uint2*)(xw + 0 * 4096) = H;
      *(uint2*)(xw + 1 * 4096) = M;
      *(uint2*)(xw + 2 * 4096) = L;
    }
    // 5) flush f32 -> f64 every 2 tiles (64 k)
    if (t & 1) {
#pragma unroll
      for (int rt = 0; rt < 2; ++rt)
#pragma unroll
        for (int ct = 0; ct < 4; ++ct) {
#pragma unroll
          for (int r = 0; r < 4; ++r) acc[rt][ct][r] += (double)D[rt][ct][r];
          D[rt][ct] = (f32x4){0.f, 0.f, 0.f, 0.f};
        }
    }
    // 6) LDS-only barrier: B prefetch loads stay in flight across it (T4)
    block_sync_lds_only();
    if (t + 2 < NT) bo_n += BTILE;   // clamp: last iteration re-reads tile NT-1
  }
#undef P8
#undef MM

  // ---- epilogue: f64 sigmoid + bias -> sc (aliases staging LDS) ----
#pragma unroll
  for (int rt = 0; rt < 2; ++rt)
#pragma unroll
    for (int ct = 0; ct < 4; ++ct) {
      const int col = wc * 64 + ct * 16 + l15;
      const double bd = (double)bias[col];
#pragma unroll
      for (int r = 0; r < 4; ++r) {
        const int row = wr * 32 + rt * 16 + (lane >> 4) * 4 + r;
        const double s = 1.0 / (1.0 + exp(-acc[rt][ct][r]));  // original score
        sc[row * 257 + col] = s + bd;                         // biased, for ranking
      }
    }
  __syncthreads();

  // ---- routing: one lane per token (verbatim from the passing kernels) ----
  if (tid < BM) {
    double* row = sc + tid * 257;
    double gs[NGRP];
#pragma unroll
    for (int g = 0; g < NGRP; ++g) {
      double m1 = -1e300, m2 = -1e300;
      for (int e = 0; e < GSZ; ++e) {
        double v = row[g * GSZ + e];
        if (v > m1) { m2 = m1; m1 = v; }
        else if (v > m2) { m2 = v; }
      }
      gs[g] = m1 + m2;
    }
    unsigned msk = 0;
#pragma unroll
    for (int g = 0; g < NGRP; ++g) {
      int cnt = 0;
#pragma unroll
      for (int h = 0; h < NGRP; ++h)
        cnt += ((gs[h] > gs[g]) || (gs[h] == gs[g] && h > g)) ? 1 : 0;
      if (cnt < TOPKG) msk |= (1u << g);
    }
    int g0 = __ffs(msk) - 1; msk &= msk - 1;
    int g1 = __ffs(msk) - 1; msk &= msk - 1;
    int g2 = __ffs(msk) - 1; msk &= msk - 1;
    int g3 = __ffs(msk) - 1;

    double wv[TOPKE];
    float iv[TOPKE];
#pragma unroll
    for (int r8 = 0; r8 < TOPKE; ++r8) {
      double best = -1e300;
      int bi = 0;
      {
        int gg = g0;
        for (int e = 0; e < GSZ; ++e) { double v = row[gg * GSZ + e]; if (v >= best) { best = v; bi = gg * GSZ + e; } }
        gg = g1;
        for (int e = 0; e < GSZ; ++e) { double v = row[gg * GSZ + e]; if (v >= best) { best = v; bi = gg * GSZ + e; } }
        gg = g2;
        for (int e = 0; e < GSZ; ++e) { double v = row[gg * GSZ + e]; if (v >= best) { best = v; bi = gg * GSZ + e; } }
        gg = g3;
        for (int e = 0; e < GSZ; ++e) { double v = row[gg * GSZ + e]; if (v >= best) { best = v; bi = gg * GSZ + e; } }
      }
      row[bi] = -1e300;
      wv[7 - r8] = best - (double)bias[bi];
      iv[7 - r8] = (float)bi;
    }
    double sum = 0.0;
#pragma unroll
    for (int p = 0; p < TOPKE; ++p) sum += wv[p];
    const double den = sum + 1e-20;
    const long trow = bm0 + tid;
#pragma unroll
    for (int p = 0; p < TOPKE; ++p) {
      outw[trow * 8 + p] = (float)(wv[p] / den * 2.5);
      outi[trow * 8 + p] = iv[p];
    }
  }
}

// ================= fallback: round-2 f64-VALU kernel (known-PASS) ============
#define BMF  64
#define BKF 16
#define LXSF 68
__global__ __launch_bounds__(256, 1) void moe_gate_f64(
    const float* __restrict__ x, const float* __restrict__ wgt,
    const float* __restrict__ bias, float* __restrict__ outw,
    float* __restrict__ outi) {
  __shared__ __align__(16) unsigned char smem[64 * 257 * 8];
  float* lw = (float*)smem;
  float* lx = (float*)(smem + 32768);
  double* sc = (double*)smem;
  const int tid = threadIdx.x;
  const long bm0 = (long)blockIdx.x * BMF;
  const int rg = tid >> 5;
  const int cg = tid & 31;
  const int sxr = tid >> 2;
  const int sxj = (tid & 3) << 2;
  const float* xrow = x + (bm0 + sxr) * (long)DIMK + sxj;
  const float* wrow = wgt + (long)tid * DIMK;
  double acc[8][8];
#pragma unroll
  for (int i = 0; i < 8; ++i)
#pragma unroll
    for (int j = 0; j < 8; ++j) acc[i][j] = 0.0;
#define LWF(b, k, e) lw[((b)*BKF + (k)) * NEXP + (e)]
#define LXF(b, k, r) lx[((b)*BKF + (k)) * LXSF + (r)]
  {
    float4 xv = *(const float4*)(xrow);
#pragma unroll
    for (int c = 0; c < 4; ++c) LXF(0, sxj + c, sxr) = ((const float*)&xv)[c];
#pragma unroll
    for (int jj = 0; jj < 4; ++jj) {
      float4 wv = *(const float4*)(wrow + jj * 4);
#pragma unroll
      for (int c = 0; c < 4; ++c) LWF(0, jj * 4 + c, tid) = ((const float*)&wv)[c];
    }
  }
  __syncthreads();
  const int NTF = DIMK / BKF;
  for (int kt = 0; kt < NTF; ++kt) {
    const int b = kt & 1;
    if (kt + 1 < NTF) {
      const int k0 = (kt + 1) * BKF;
      const int nb = b ^ 1;
      float4 xv = *(const float4*)(xrow + k0);
      float4 wv0 = *(const float4*)(wrow + k0);
      float4 wv1 = *(const float4*)(wrow + k0 + 4);
      float4 wv2 = *(const float4*)(wrow + k0 + 8);
      float4 wv3 = *(const float4*)(wrow + k0 + 12);
#pragma unroll
      for (int c = 0; c < 4; ++c) LXF(nb, sxj + c, sxr) = ((const float*)&xv)[c];
#pragma unroll
      for (int c = 0; c < 4; ++c) LWF(nb, 0 + c, tid) = ((const float*)&wv0)[c];
#pragma unroll
      for (int c = 0; c < 4; ++c) LWF(nb, 4 + c, tid) = ((const float*)&wv1)[c];
#pragma unroll
      for (int c = 0; c < 4; ++c) LWF(nb, 8 + c, tid) = ((const float*)&wv2)[c];
#pragma unroll
      for (int c = 0; c < 4; ++c) LWF(nb, 12 + c, tid) = ((const float*)&wv3)[c];
    }
#pragma unroll
    for (int k = 0; k < BKF; ++k) {
      float4 a0 = *(const float4*)(&LXF(b, k, rg * 8));
      float4 a1 = *(const float4*)(&LXF(b, k, rg * 8 + 4));
      double ad[8] = {(double)a0.x, (double)a0.y, (double)a0.z, (double)a0.w,
                      (double)a1.x, (double)a1.y, (double)a1.z, (double)a1.w};
      double bd[8];
#pragma unroll
      for (int j = 0; j < 4; ++j) {
        float2 bb = *(const float2*)(&LWF(b, k, cg * 2 + 64 * j));
        bd[2 * j] = (double)bb.x;
        bd[2 * j + 1] = (double)bb.y;
      }
#pragma unroll
      for (int i = 0; i < 8; ++i)
#pragma unroll
        for (int j = 0; j < 8; ++j) acc[i][j] += ad[i] * bd[j];
    }
    __syncthreads();
  }
  double bc[8];
#pragma unroll
  for (int j = 0; j < 4; ++j) {
    bc[2 * j] = (double)bias[cg * 2 + 64 * j];
    bc[2 * j + 1] = (double)bias[cg * 2 + 64 * j + 1];
  }
#pragma unroll
  for (int i = 0; i < 8; ++i) {
    const int r = rg * 8 + i;
#pragma unroll
    for (int jq = 0; jq < 8; ++jq) {
      const int col = cg * 2 + 64 * (jq >> 1) + (jq & 1);
      double s = 1.0 / (1.0 + exp(-acc[i][jq]));
      sc[r * 257 + col] = s + bc[jq];
    }
  }
  __syncthreads();
  if (tid < BMF) {
    double* row = sc + tid * 257;
    double gs[NGRP];
#pragma unroll
    for (int g = 0; g < NGRP; ++g) {
      double m1 = -1e300, m2 = -1e300;
      for (int e = 0; e < GSZ; ++e) {
        double v = row[g * GSZ + e];
        if (v > m1) { m2 = m1; m1 = v; }
        else if (v > m2) { m2 = v; }
      }
      gs[g] = m1 + m2;
    }
    unsigned msk = 0;
#pragma unroll
    for (int g = 0; g < NGRP; ++g) {
      int cnt = 0;
#pragma unroll
      for (int h = 0; h < NGRP; ++h)
        cnt += ((gs[h] > gs[g]) || (gs[h] == gs[g] && h > g)) ? 1 : 0;
      if (cnt < TOPKG) msk |= (1u << g);
    }
    int g0 = __ffs(msk) - 1; msk &= msk - 1;
    int g1 = __ffs(msk) - 1; msk &= msk - 1;
    int g2 = __ffs(msk) - 1; msk &= msk - 1;
    int g3 = __ffs(msk) - 1;
    double wv[TOPKE];
    float iv[TOPKE];
#pragma unroll
    for (int r8 = 0; r8 < TOPKE; ++r8) {
      double best = -1e300;
      int bi = 0;
      {
        int gg = g0;
        for (int e = 0; e < GSZ; ++e) { double v = row[gg * GSZ + e]; if (v >= best) { best = v; bi = gg * GSZ + e; } }
        gg = g1;
        for (int e = 0; e < GSZ; ++e) { double v = row[gg * GSZ + e]; if (v >= best) { best = v; bi = gg * GSZ + e; } }
        gg = g2;
        for (int e = 0; e < GSZ; ++e) { double v = row[gg * GSZ + e]; if (v >= best) { best = v; bi = gg * GSZ + e; } }
        gg = g3;
        for (int e = 0; e < GSZ; ++e) { double v = row[gg * GSZ + e]; if (v >= best) { best = v; bi = gg * GSZ + e; } }
      }
      row[bi] = -1e300;
      wv[7 - r8] = best - (double)bias[bi];
      iv[7 - r8] = (float)bi;
    }
    double sum = 0.0;
#pragma unroll
    for (int p = 0; p < TOPKE; ++p) sum += wv[p];
    const double den = sum + 1e-20;
    const long trow = bm0 + tid;
#pragma unroll
    for (int p = 0; p < TOPKE; ++p) {
      outw[trow * 8 + p] = (float)(wv[p] / den * 2.5);
      outi[trow * 8 + p] = iv[p];
    }
  }
}

extern "C" void kernel_launch(void* const* d_in, const int* in_sizes, int n_in,
                              void* d_out, int out_size, void* d_ws, size_t ws_size,
                              hipStream_t stream) {
  const float* x = (const float*)d_in[0];
  const float* w = (const float*)d_in[1];
  const float* b = (const float*)d_in[2];
  const int ntok = in_sizes[0] / DIMK;  // 16384
  float* outw = (float*)d_out;
  float* outi = outw + (size_t)ntok * 8;
  if (ws_size >= WS_NEED) {
    hipLaunchKernelGGL(w_split_kernel, dim3(512), dim3(256), 0, stream,
                       w, (unsigned char*)d_ws);
    hipLaunchKernelGGL(moe_gate_mfma, dim3(ntok / BM), dim3(512), 0, stream,
                       x, (const unsigned char*)d_ws, b, outw, outi);
  } else {
    hipLaunchKernelGGL(moe_gate_f64, dim3(ntok / 64), dim3(256), 0, stream,
                       x, w, b, outw, outi);
  }
}